// Round 10
// baseline (122.324 us; speedup 1.0000x reference)
//
#include <hip/hip_runtime.h>
#include <stdint.h>
#include <stddef.h>
#include <math.h>

// SIR scan: B=16384 batches, T=2048 steps, F=2 (beta,gamma), fp32.
// Round 10: 4 INDEPENDENT single-wave pipelines per CU, register-path
// loads (no global_load_lds), zero inter-wave sync.
//   - 1024 blocks x 64 threads; each wave owns 16 batches.
//   - per chunk (C=64 steps, 8 KB): 8x global_load_dwordx4 (1 KB
//     contiguous each) -> regs; ds_write_b128 -> private LDS (transpose);
//     lgkmcnt; swizzled ds_read_b128; R9 algebra.
//   - lanes 16-63 duplicate lanes 0-15 (broadcast LDS reads, free);
//     only lanes 0-15 store.
// Tests: does per-CU read rate scale with independent REG-load waves
// (vs R6's null for DMA waves -> shared DMA-return-unit suspicion)?

#define T_STEPS 2048
#define C_STEPS 64                   // timesteps per chunk
#define NCHUNK  (T_STEPS / C_STEPS)  // 32
#define BPW     16                   // batches per wave/block
#define SLOTS   (C_STEPS / 2)        // 32 float4 slots per row per chunk
#define LPC     8                    // loads per chunk (rows 2j,2j+1 each)

#define INV_POP 1e-6f

// Load chunk c into regs: load j covers rows {2j,2j+1} (512 B each,
// 1 KB contiguous per instruction). Lane l -> row 2j+(l>>5), slot l&31.
__device__ __forceinline__ void load_chunk(const float* __restrict__ in,
                                           int b0, int c, int lane, float4* r)
{
    const int hi = lane >> 5;          // 0/1
    const int s  = lane & 31;          // slot within row
#pragma unroll
    for (int j = 0; j < LPC; ++j) {
        const float* g = in
            + (size_t)(b0 + 2 * j + hi) * (T_STEPS * 2)
            + (size_t)c * (C_STEPS * 2)
            + (size_t)(s * 4);
        r[j] = *(const float4*)g;
    }
}

// Transpose-stage regs -> LDS. LDS slot q of row holds global slot
// q ^ (row&7); per instr 64 lanes write 1 KB -> 8 word-accesses/bank
// (the wave64-b128 inherent floor).
__device__ __forceinline__ void write_chunk(float4* lds, int lane,
                                            const float4* r)
{
    const int hi = lane >> 5;
    const int s  = lane & 31;
#pragma unroll
    for (int j = 0; j < LPC; ++j) {
        const int row = 2 * j + hi;
        lds[row * SLOTS + (s ^ (row & 7))] = r[j];
    }
}

// Consume one chunk: lane's row rr = lane&15 (4x broadcast duplication).
// Read lds slot s^(rr&7): rows rr and rr+8 pair per bank-quad (2-way,
// free), duplicates broadcast. Grouped unroll (4 slots) keeps ds_read
// hoisting bounded -> no VGPR blow-up (R7 lesson).
__device__ __forceinline__ void compute_chunk(const float4* lds, int rr,
                                              float& S, float& I, float& rsum)
{
    const int swz = rr & 7;
    const float4* row = lds + rr * SLOTS;
#pragma unroll 1
    for (int g = 0; g < SLOTS / 4; ++g) {
#pragma unroll
        for (int k = 0; k < 4; ++k) {
            const int s = g * 4 + k;
            const float4 v = row[s ^ swz];  // steps 2s, 2s+1

            float u  = v.x * INV_POP;
            float t1 = u * S;
            float t2 = u * I;
            float w  = fmaf(-v.y, I, I);
            rsum     = fmaf(v.y, I, rsum);
            I = fmaf(I, t1, w);
            S = fmaf(-t2, S, S);

            u  = v.z * INV_POP;
            t1 = u * S;
            t2 = u * I;
            w  = fmaf(-v.w, I, I);
            rsum = fmaf(v.w, I, rsum);
            I = fmaf(I, t1, w);
            S = fmaf(-t2, S, S);
        }
    }
}

#define LGKM0() asm volatile("s_waitcnt lgkmcnt(0)" ::: "memory")

__global__ __launch_bounds__(64)
void sir_scan_kernel(const float* __restrict__ in, const float* __restrict__ init,
                     float* __restrict__ out, int half)
{
    __shared__ float4 lds[BPW * SLOTS];   // 8 KB, single buffer (transient)

    const int tid = threadIdx.x;
    const int b0  = blockIdx.x * BPW;
    const int rr  = tid & 15;             // this lane's batch row (4x dup)
    const int gb  = b0 + rr;

    float S  = init[gb * 3 + 0];
    float I  = init[gb * 3 + 1];
    float R0 = init[gb * 3 + 2];
    float rsum = 0.0f;

    // two named reg buffers (rule #20: all indexing compile-time)
    float4 rA[LPC], rB[LPC];
    load_chunk(in, b0, 0, tid, rA);       // chunk 0 -> rA
    load_chunk(in, b0, 1, tid, rB);       // chunk 1 -> rB

    // Steady state (per half-iteration):
    //   ds_write(rX)       <- compiler waits vmcnt for rX's loads only
    //   LGKM0              <- write landed (same-wave ordering)
    //   issue load rX <- c+2 (WAR-safe: write consumed rX)
    //   compute chunk c from LDS (loads for c+1, c+2 in flight: 16 KB)
#pragma unroll 1
    for (int c = 0; c < NCHUNK; c += 2) {
        write_chunk(lds, tid, rA);
        LGKM0();
        if (c + 2 < NCHUNK) load_chunk(in, b0, c + 2, tid, rA);
        compute_chunk(lds, rr, S, I, rsum);

        write_chunk(lds, tid, rB);
        LGKM0();
        if (c + 3 < NCHUNK) load_chunk(in, b0, c + 3, tid, rB);
        compute_chunk(lds, rr, S, I, rsum);
    }

    if (tid < BPW) {
        const float R = R0 + rsum;
        out[gb * 3 + 0] = S;
        out[gb * 3 + 1] = I;
        out[gb * 3 + 2] = R;
        out[half + gb * 3 + 0] = S;
        out[half + gb * 3 + 1] = I;
        out[half + gb * 3 + 2] = R;
    }
}

extern "C" void kernel_launch(void* const* d_in, const int* in_sizes, int n_in,
                              void* d_out, int out_size, void* d_ws, size_t ws_size,
                              hipStream_t stream) {
    (void)in_sizes; (void)n_in; (void)d_ws; (void)ws_size;
    const float* in   = (const float*)d_in[0];   // (B, T, 2) fp32
    const float* init = (const float*)d_in[1];   // (B, 3)    fp32
    float* out        = (float*)d_out;           // 2 x (B, 3) fp32, concatenated
    const int half = out_size / 2;

    dim3 grid(16384 / BPW);   // 1024 blocks -> 4 independent waves per CU
    dim3 block(64);           // 1 wave, fully self-contained
    sir_scan_kernel<<<grid, block, 0, stream>>>(in, init, out, half);
}